// Round 11
// baseline (36876.010 us; speedup 1.0000x reference)
//
#include <hip/hip_runtime.h>

#define DD 1024        // hidden size
#define TT 8192        // sequence length
#define NBLK 128       // grid blocks
#define NTHR 512       // 8 waves per block
#define RPB 8          // rows per block (one per wave)
#define WLDS (RPB * 4 * DD)            // 32768 floats = 128 KB weights
#define LDSB ((WLDS + 4 * DD) * 4)     // + 16 KB dbuf h/c stage = 144 KB

typedef unsigned long long u64;

__device__ __forceinline__ float fast_sigmoid(float x) {
  x = fminf(fmaxf(x, -30.0f), 30.0f);
  return 1.0f / (1.0f + __expf(-x));
}

__device__ __forceinline__ float fast_tanh(float x) {
  x = fminf(fmaxf(x, -15.0f), 15.0f);
  float e = __expf(2.0f * x);
  return (e - 1.0f) / (e + 1.0f);
}

__device__ __forceinline__ u64 ld_cp(const u64* p) {
  return __hip_atomic_load(p, __ATOMIC_RELAXED, __HIP_MEMORY_SCOPE_AGENT);
}

// Persistent LSTM. 128KB LDS weights + 16KB dbuf SoA hc stage.
// R11 = R10's tagged-data single-RTT protocol + R8's poller topology.
//  - protocol (R10, correctness-validated): state word = {u32 tag=t+1 |
//    f32 value}, ONE relaxed agent 8B atomic. No flags, no producer vmcnt
//    drain, no end-of-step barrier. Detect IS the fetch (one RTT).
//    Ring-2 safe: a block can only write step t+1 (tag t+2) after its t+1
//    fetch saw tag>=t+1 on ALL words, which requires every block to have
//    finished step t (including its reads) — so no live slot is overwritten.
//  - topology (R8, perf-validated): ONLY wave 0 spin-fetches (8192 pollers
//    device-wide, not 65536 — R10's all-wave spin flooded the IF$ and
//    doubled FETCH_SIZE), round-based retry of stale words only, s_sleep(1)
//    backoff. Then SoA LDS stage (R9: conflict-free), one __syncthreads,
//    8 waves MAC from LDS.
__global__ __launch_bounds__(NTHR, 1) void lstm_seq(
    const float* __restrict__ X,      // [T, D]
    const float* __restrict__ enc_h,  // [D]
    const float* __restrict__ enc_c,  // [D]
    const float* __restrict__ Wf, const float* __restrict__ bf_,
    const float* __restrict__ Wi, const float* __restrict__ bi_,
    const float* __restrict__ Wc, const float* __restrict__ bc_,
    const float* __restrict__ Wo, const float* __restrict__ bo_,
    float* __restrict__ out,          // [T, D] h_t rows
    u64* __restrict__ hw,             // [2][D] tagged h words
    u64* __restrict__ cw)             // [2][D] tagged c words
{
  extern __shared__ float lds[];      // weights | h stage [2][D] | c stage [2][D]
  const int wv   = threadIdx.x >> 6;  // wave = local row 0..7
  const int lane = threadIdx.x & 63;
  const int j    = blockIdx.x * RPB + wv;

  // ---- stage h-part weights into LDS (once); gate order f,i,o,C ----
  for (int idx = threadIdx.x; idx < RPB * 4 * 256; idx += NTHR) {
    const int r = idx >> 10, g = (idx >> 8) & 3, q = idx & 255;
    const int row = blockIdx.x * RPB + r;
    const float* ws = (g == 0) ? Wf : (g == 1) ? Wi : (g == 2) ? Wo : Wc;
    *(float4*)&lds[idx * 4] = *(const float4*)(ws + (size_t)row * 2048 + q * 4);
  }

  // ---- per-lane constant weights in registers (x-parts + c-part) ----
  float wxf[16], wxi[16], wxo[16], wcc[16];
#pragma unroll
  for (int kb = 0; kb < 4; ++kb) {
    const int k = 1024 + kb * 256 + lane * 4;
    *(float4*)&wxf[kb*4] = *(const float4*)(Wf + (size_t)j * 2048 + k);
    *(float4*)&wxi[kb*4] = *(const float4*)(Wi + (size_t)j * 2048 + k);
    *(float4*)&wxo[kb*4] = *(const float4*)(Wo + (size_t)j * 2048 + k);
    *(float4*)&wcc[kb*4] = *(const float4*)(Wc + (size_t)j * 2048 + k);
  }
  const float Bf = bf_[j], Bi = bi_[j], Bc = bc_[j], Bo = bo_[j];
  const float* lw = lds + wv * 4096;       // this wave's [4][1024] h-weights
  float* hst = lds + WLDS;                 // [2][1024] staged h
  float* cst = lds + WLDS + 2 * DD;        // [2][1024] staged c

  float cj = enc_c[j];  // register carry of this row's cell state

  __syncthreads();

  // x_0 preload; thereafter x_{t+1} is prefetched a full step ahead
  float4 xc0, xc1, xc2, xc3;
  {
    const float* xq = X + lane * 4;
    xc0 = *(const float4*)(xq);       xc1 = *(const float4*)(xq + 256);
    xc2 = *(const float4*)(xq + 512); xc3 = *(const float4*)(xq + 768);
  }

  for (int t = 0; t < TT; ++t) {
    // issue next-step x loads (HBM latency hides under this whole step)
    float4 xn0, xn1, xn2, xn3;
    {
      const size_t tn = (t + 1 < TT) ? (size_t)(t + 1) : (size_t)t;
      const float* xq = X + tn * DD + lane * 4;
      xn0 = *(const float4*)(xq);       xn1 = *(const float4*)(xq + 256);
      xn2 = *(const float4*)(xq + 512); xn3 = *(const float4*)(xq + 768);
    }

    // x-part MACs (barrier-independent; biases added post-reduce — R3 lesson)
    float aF = 0.0f, aI = 0.0f, aO = 0.0f, aC = 0.0f;
#pragma unroll
    for (int kb = 0; kb < 4; ++kb) {
      const float4 xv = (kb==0)?xc0:(kb==1)?xc1:(kb==2)?xc2:xc3;
      const int b = kb * 4;
      aF += wxf[b]*xv.x + wxf[b+1]*xv.y + wxf[b+2]*xv.z + wxf[b+3]*xv.w;
      aI += wxi[b]*xv.x + wxi[b+1]*xv.y + wxi[b+2]*xv.z + wxi[b+3]*xv.w;
      aO += wxo[b]*xv.x + wxo[b+1]*xv.y + wxo[b+2]*xv.z + wxo[b+3]*xv.w;
    }

    if (t > 0) {
      const unsigned want = (unsigned)t;   // step t-1 data carries tag t
      const int rp = (t - 1) & 1;          // ring slot written by step t-1

      if (wv == 0) {  // wave 0 only: spin-fetch all 2048 tagged words
        const u64* hsrc = hw + (size_t)rp * DD + lane;
        const u64* csrc = cw + (size_t)rp * DD + lane;
        u64 vh[16], vc[16];
#pragma unroll
        for (int q = 0; q < 16; ++q) vh[q] = ld_cp(hsrc + q * 64);
#pragma unroll
        for (int q = 0; q < 16; ++q) vc[q] = ld_cp(csrc + q * 64);
        for (;;) {
          bool ok = true;
#pragma unroll
          for (int q = 0; q < 16; ++q) {
            ok &= ((unsigned)(vh[q] >> 32) >= want);
            ok &= ((unsigned)(vc[q] >> 32) >= want);
          }
          if (__all(ok)) break;
          __builtin_amdgcn_s_sleep(1);
#pragma unroll
          for (int q = 0; q < 16; ++q) {
            if ((unsigned)(vh[q] >> 32) < want) vh[q] = ld_cp(hsrc + q * 64);
            if ((unsigned)(vc[q] >> 32) < want) vc[q] = ld_cp(csrc + q * 64);
          }
        }
        // stage SoA: lane writes float at lane*4B + q*256B — conflict-free
#pragma unroll
        for (int q = 0; q < 16; ++q) {
          hst[rp * DD + q * 64 + lane] = __uint_as_float((unsigned)vh[q]);
          cst[rp * DD + q * 64 + lane] = __uint_as_float((unsigned)vc[q]);
        }
      }
      __syncthreads();  // the ONLY per-step barrier: stage -> MAC

      // MACs from SoA stage: contiguous b128 reads, conflict-free
#pragma unroll
      for (int kb = 0; kb < 4; ++kb) {
        const int o = kb * 256 + lane * 4;
        const float4 hv = *(const float4*)&hst[rp * DD + o];
        const float4 cc = *(const float4*)&cst[rp * DD + o];
        const float4 wF = *(const float4*)&lw[o];
        const float4 wI = *(const float4*)&lw[1024 + o];
        const float4 wO = *(const float4*)&lw[2048 + o];
        const float4 wC = *(const float4*)&lw[3072 + o];
        const int b = kb * 4;
        aF += wF.x*hv.x + wF.y*hv.y + wF.z*hv.z + wF.w*hv.w;
        aI += wI.x*hv.x + wI.y*hv.y + wI.z*hv.z + wI.w*hv.w;
        aO += wO.x*hv.x + wO.y*hv.y + wO.z*hv.z + wO.w*hv.w;
        aC += wC.x*hv.x + wC.y*hv.y + wC.z*hv.z + wC.w*hv.w;
        aC += wcc[b]*cc.x + wcc[b+1]*cc.y + wcc[b+2]*cc.z + wcc[b+3]*cc.w;
      }
    } else {
      // t == 0: initial state straight from inputs (plain loads)
      const float* hp = enc_h + lane * 4;
      const float* cp = enc_c + lane * 4;
#pragma unroll
      for (int kb = 0; kb < 4; ++kb) {
        const int o = kb * 256 + lane * 4;
        const float4 hv = *(const float4*)(hp + kb * 256);
        const float4 cc = *(const float4*)(cp + kb * 256);
        const float4 wF = *(const float4*)&lw[o];
        const float4 wI = *(const float4*)&lw[1024 + o];
        const float4 wO = *(const float4*)&lw[2048 + o];
        const float4 wC = *(const float4*)&lw[3072 + o];
        const int b = kb * 4;
        aF += wF.x*hv.x + wF.y*hv.y + wF.z*hv.z + wF.w*hv.w;
        aI += wI.x*hv.x + wI.y*hv.y + wI.z*hv.z + wI.w*hv.w;
        aO += wO.x*hv.x + wO.y*hv.y + wO.z*hv.z + wO.w*hv.w;
        aC += wC.x*hv.x + wC.y*hv.y + wC.z*hv.z + wC.w*hv.w;
        aC += wcc[b]*cc.x + wcc[b+1]*cc.y + wcc[b+2]*cc.z + wcc[b+3]*cc.w;
      }
    }

#pragma unroll
    for (int m = 32; m >= 1; m >>= 1) {
      aF += __shfl_xor(aF, m, 64);
      aI += __shfl_xor(aI, m, 64);
      aO += __shfl_xor(aO, m, 64);
      aC += __shfl_xor(aC, m, 64);
    }

    // biases added exactly once, post-reduction
    const float fg = fast_sigmoid(aF + Bf);
    const float ig = fast_sigmoid(aI + Bi);
    const float og = fast_sigmoid(aO + Bo);
    const float ct = fast_tanh(aC + Bc);
    const float cn = fg * cj + ig * ct;
    const float hn = og * fast_tanh(cn);
    cj = cn;

    if (lane == 0) {
      out[(size_t)t * DD + j] = hn;  // plain store; host reads after kernel end
      const u64 tag = ((u64)(unsigned)(t + 1)) << 32;
      __hip_atomic_store(&hw[(size_t)(t & 1) * DD + j],
                         tag | (u64)__float_as_uint(hn),
                         __ATOMIC_RELAXED, __HIP_MEMORY_SCOPE_AGENT);
      __hip_atomic_store(&cw[(size_t)(t & 1) * DD + j],
                         tag | (u64)__float_as_uint(cn),
                         __ATOMIC_RELAXED, __HIP_MEMORY_SCOPE_AGENT);
    }
    // no end-of-step barrier: tagged data is the sync; LDS stage is dbuf'd
    xc0 = xn0; xc1 = xn1; xc2 = xn2; xc3 = xn3;
  }
}

extern "C" void kernel_launch(void* const* d_in, const int* in_sizes, int n_in,
                              void* d_out, int out_size, void* d_ws, size_t ws_size,
                              hipStream_t stream) {
  const float* X    = (const float*)d_in[0];
  const float* eh   = (const float*)d_in[1];
  const float* ec   = (const float*)d_in[2];
  const float* Wf   = (const float*)d_in[3];
  const float* bf_  = (const float*)d_in[4];
  const float* Wi   = (const float*)d_in[5];
  const float* bi_  = (const float*)d_in[6];
  const float* Wc   = (const float*)d_in[7];
  const float* bc_  = (const float*)d_in[8];
  const float* Wo   = (const float*)d_in[9];
  const float* bo_  = (const float*)d_in[10];
  float* out = (float*)d_out;

  u64* hw = (u64*)d_ws;                         // [2][1024] tagged h (16 KB)
  u64* cw = (u64*)((char*)d_ws + 16384);        // [2][1024] tagged c (16 KB)

  hipMemsetAsync(d_ws, 0, 32768, stream);       // zero tags each call

  hipFuncSetAttribute((const void*)lstm_seq,
                      hipFuncAttributeMaxDynamicSharedMemorySize, LDSB);

  void* args[] = {(void*)&X, (void*)&eh, (void*)&ec,
                  (void*)&Wf, (void*)&bf_, (void*)&Wi, (void*)&bi_,
                  (void*)&Wc, (void*)&bc_, (void*)&Wo, (void*)&bo_,
                  (void*)&out, (void*)&hw, (void*)&cw};
  hipError_t e = hipLaunchCooperativeKernel((const void*)lstm_seq,
                                            dim3(NBLK), dim3(NTHR),
                                            args, LDSB, stream);
  if (e != hipSuccess) {
    // plain-launch fallback: 128 blocks x 144KB LDS => 1 block/CU, co-resident
    lstm_seq<<<dim3(NBLK), dim3(NTHR), LDSB, stream>>>(
        X, eh, ec, Wf, bf_, Wi, bi_, Wc, bc_, Wo, bo_, out, hw, cw);
  }
}

// Round 12
// 24141.243 us; speedup vs baseline: 1.5275x; 1.5275x over previous
//
#include <hip/hip_runtime.h>

#define DD 1024        // hidden size
#define TT 8192        // sequence length
#define NBLK 128       // grid blocks == barrier participants
#define NTHR 512       // 8 waves per block
#define RPB 8          // rows per block (one per wave)
#define WLDS (RPB * 4 * DD)            // 32768 floats = 128 KB weights
#define LDSB ((WLDS + 4 * DD) * 4)     // + 16 KB dbuf SoA stage = 144 KB

typedef unsigned long long u64;

__device__ __forceinline__ float fast_sigmoid(float x) {
  x = fminf(fmaxf(x, -30.0f), 30.0f);
  return 1.0f / (1.0f + __expf(-x));
}

__device__ __forceinline__ float fast_tanh(float x) {
  x = fminf(fmaxf(x, -15.0f), 15.0f);
  float e = __expf(2.0f * x);
  return (e - 1.0f) / (e + 1.0f);
}

union HC { u64 u; float2 f; };

// Persistent LSTM. 128KB LDS weights + 16KB dbuf SoA hc stage.
// R12 = R8's validated sync structure (best measured: 23.3ms) with exactly
// two fixes, nothing else changed:
//  - SoA stage (R9-validated): separate h/c arrays kill R8's 4.7e8 LDS
//    bank conflicts (AoS float2 read as float4 = 32B/lane stride).
//  - no s_sleep in poll: sleep configs (R8,R11) showed 2-6x profiled-replay
//    jitter; no-sleep (R7,R9) rock-stable.
// Sync law (R4/R8/R9/R10/R11): spin on minimal hot lines (128 packed flags
// = 2 lines), move bulk data exactly once, spinners <= 1 wave/block.
__global__ __launch_bounds__(NTHR, 1) void lstm_seq(
    const float* __restrict__ X,      // [T, D]
    const float* __restrict__ enc_h,  // [D]
    const float* __restrict__ enc_c,  // [D]
    const float* __restrict__ Wf, const float* __restrict__ bf_,
    const float* __restrict__ Wi, const float* __restrict__ bi_,
    const float* __restrict__ Wc, const float* __restrict__ bc_,
    const float* __restrict__ Wo, const float* __restrict__ bo_,
    float* __restrict__ out,          // [T, D] h_t rows
    u64* __restrict__ hcbuf,          // [2][D] ring of packed {h,c}
    unsigned* __restrict__ flags)     // [NBLK] packed (512 B)
{
  extern __shared__ float lds[];      // weights | hst[2][D] | cst[2][D]
  const int wv   = threadIdx.x >> 6;  // wave = local row 0..7
  const int lane = threadIdx.x & 63;
  const int j    = blockIdx.x * RPB + wv;

  // ---- stage h-part weights into LDS (once); gate order f,i,o,C ----
  for (int idx = threadIdx.x; idx < RPB * 4 * 256; idx += NTHR) {
    const int r = idx >> 10, g = (idx >> 8) & 3, q = idx & 255;
    const int row = blockIdx.x * RPB + r;
    const float* ws = (g == 0) ? Wf : (g == 1) ? Wi : (g == 2) ? Wo : Wc;
    *(float4*)&lds[idx * 4] = *(const float4*)(ws + (size_t)row * 2048 + q * 4);
  }

  // ---- per-lane constant weights in registers (x-parts + c-part) ----
  float wxf[16], wxi[16], wxo[16], wcc[16];
#pragma unroll
  for (int kb = 0; kb < 4; ++kb) {
    const int k = 1024 + kb * 256 + lane * 4;
    *(float4*)&wxf[kb*4] = *(const float4*)(Wf + (size_t)j * 2048 + k);
    *(float4*)&wxi[kb*4] = *(const float4*)(Wi + (size_t)j * 2048 + k);
    *(float4*)&wxo[kb*4] = *(const float4*)(Wo + (size_t)j * 2048 + k);
    *(float4*)&wcc[kb*4] = *(const float4*)(Wc + (size_t)j * 2048 + k);
  }
  const float Bf = bf_[j], Bi = bi_[j], Bc = bc_[j], Bo = bo_[j];
  const float* lw = lds + wv * 4096;       // this wave's [4][1024] h-weights
  float* hst = lds + WLDS;                 // [2][1024] staged h (SoA)
  float* cst = lds + WLDS + 2 * DD;        // [2][1024] staged c (SoA)

  float cj = enc_c[j];  // register carry of this row's cell state

  __syncthreads();

  // x_0 preload; thereafter x_{t+1} is prefetched a full step ahead
  float4 xc0, xc1, xc2, xc3;
  {
    const float* xq = X + lane * 4;
    xc0 = *(const float4*)(xq);       xc1 = *(const float4*)(xq + 256);
    xc2 = *(const float4*)(xq + 512); xc3 = *(const float4*)(xq + 768);
  }

  for (int t = 0; t < TT; ++t) {
    // issue next-step x loads (HBM latency hides under this whole step)
    float4 xn0, xn1, xn2, xn3;
    {
      const size_t tn = (t + 1 < TT) ? (size_t)(t + 1) : (size_t)t;
      const float* xq = X + tn * DD + lane * 4;
      xn0 = *(const float4*)(xq);       xn1 = *(const float4*)(xq + 256);
      xn2 = *(const float4*)(xq + 512); xn3 = *(const float4*)(xq + 768);
    }

    // x-part MACs (barrier-independent; biases added post-reduce — R3 lesson)
    float aF = 0.0f, aI = 0.0f, aO = 0.0f, aC = 0.0f;
#pragma unroll
    for (int kb = 0; kb < 4; ++kb) {
      const float4 xv = (kb==0)?xc0:(kb==1)?xc1:(kb==2)?xc2:xc3;
      const int b = kb * 4;
      aF += wxf[b]*xv.x + wxf[b+1]*xv.y + wxf[b+2]*xv.z + wxf[b+3]*xv.w;
      aI += wxi[b]*xv.x + wxi[b+1]*xv.y + wxi[b+2]*xv.z + wxi[b+3]*xv.w;
      aO += wxo[b]*xv.x + wxo[b+1]*xv.y + wxo[b+2]*xv.z + wxo[b+3]*xv.w;
    }

    const int rp = (t - 1) & 1;  // ring slot produced by step t-1

    if (t > 0) {
      if (wv == 0) {  // wave 0: poll 2 hot lines, then one-shot fetch+stage
        const unsigned tt = (unsigned)t;
        for (;;) {
          unsigned a = __hip_atomic_load(&flags[lane     ], __ATOMIC_RELAXED, __HIP_MEMORY_SCOPE_AGENT);
          unsigned b = __hip_atomic_load(&flags[lane + 64], __ATOMIC_RELAXED, __HIP_MEMORY_SCOPE_AGENT);
          if (__all((a >= tt) & (b >= tt))) break;
        }
        // fetch the 1024 {h,c} pairs exactly once: 16x 8B coherence loads
        const u64* src = hcbuf + (size_t)rp * DD + lane;
        u64 raw[16];
#pragma unroll
        for (int q = 0; q < 16; ++q) raw[q] = __hip_atomic_load(src + q * 64,
                                        __ATOMIC_RELAXED, __HIP_MEMORY_SCOPE_AGENT);
        // SoA stage: 4B stride-1 writes at q*256B + lane*4B — conflict-free
#pragma unroll
        for (int q = 0; q < 16; ++q) {
          HC u; u.u = raw[q];
          hst[rp * DD + q * 64 + lane] = u.f.x;
          cst[rp * DD + q * 64 + lane] = u.f.y;
        }
      }
      __syncthreads();  // stage visible to all 8 waves

      // MACs from SoA stage: contiguous b128 reads, conflict-free
#pragma unroll
      for (int kb = 0; kb < 4; ++kb) {
        const int o = kb * 256 + lane * 4;
        const float4 hv = *(const float4*)&hst[rp * DD + o];
        const float4 cc = *(const float4*)&cst[rp * DD + o];
        const float4 wF = *(const float4*)&lw[o];
        const float4 wI = *(const float4*)&lw[1024 + o];
        const float4 wO = *(const float4*)&lw[2048 + o];
        const float4 wC = *(const float4*)&lw[3072 + o];
        const int b = kb * 4;
        aF += wF.x*hv.x + wF.y*hv.y + wF.z*hv.z + wF.w*hv.w;
        aI += wI.x*hv.x + wI.y*hv.y + wI.z*hv.z + wI.w*hv.w;
        aO += wO.x*hv.x + wO.y*hv.y + wO.z*hv.z + wO.w*hv.w;
        aC += wC.x*hv.x + wC.y*hv.y + wC.z*hv.z + wC.w*hv.w;
        aC += wcc[b]*cc.x + wcc[b+1]*cc.y + wcc[b+2]*cc.z + wcc[b+3]*cc.w;
      }
    } else {
      // t == 0: initial state straight from inputs (plain loads)
      const float* hp = enc_h + lane * 4;
      const float* cp = enc_c + lane * 4;
#pragma unroll
      for (int kb = 0; kb < 4; ++kb) {
        const int o = kb * 256 + lane * 4;
        const float4 hv = *(const float4*)(hp + kb * 256);
        const float4 cc = *(const float4*)(cp + kb * 256);
        const float4 wF = *(const float4*)&lw[o];
        const float4 wI = *(const float4*)&lw[1024 + o];
        const float4 wO = *(const float4*)&lw[2048 + o];
        const float4 wC = *(const float4*)&lw[3072 + o];
        const int b = kb * 4;
        aF += wF.x*hv.x + wF.y*hv.y + wF.z*hv.z + wF.w*hv.w;
        aI += wI.x*hv.x + wI.y*hv.y + wI.z*hv.z + wI.w*hv.w;
        aO += wO.x*hv.x + wO.y*hv.y + wO.z*hv.z + wO.w*hv.w;
        aC += wC.x*hv.x + wC.y*hv.y + wC.z*hv.z + wC.w*hv.w;
        aC += wcc[b]*cc.x + wcc[b+1]*cc.y + wcc[b+2]*cc.z + wcc[b+3]*cc.w;
      }
    }

#pragma unroll
    for (int m = 32; m >= 1; m >>= 1) {
      aF += __shfl_xor(aF, m, 64);
      aI += __shfl_xor(aI, m, 64);
      aO += __shfl_xor(aO, m, 64);
      aC += __shfl_xor(aC, m, 64);
    }

    // biases added exactly once, post-reduction
    const float fg = fast_sigmoid(aF + Bf);
    const float ig = fast_sigmoid(aI + Bi);
    const float og = fast_sigmoid(aO + Bo);
    const float ct = fast_tanh(aC + Bc);
    const float cn = fg * cj + ig * ct;
    const float hn = og * fast_tanh(cn);
    cj = cn;

    if (lane == 0) {
      out[(size_t)t * DD + j] = hn;  // plain store; host reads after kernel end
      HC u; u.f = make_float2(hn, cn);
      __hip_atomic_store(hcbuf + (size_t)(t & 1) * DD + j, u.u,
                         __ATOMIC_RELAXED, __HIP_MEMORY_SCOPE_AGENT);
    }
    __syncthreads();  // each wave drains vmcnt(0): hc stores ack'd at IF$
    if (threadIdx.x == 0) {
      // relaxed: ordering provided by the per-wave vmcnt drain above
      __hip_atomic_store(&flags[blockIdx.x], (unsigned)(t + 1),
                         __ATOMIC_RELAXED, __HIP_MEMORY_SCOPE_AGENT);
    }
    xc0 = xn0; xc1 = xn1; xc2 = xn2; xc3 = xn3;
  }
}

extern "C" void kernel_launch(void* const* d_in, const int* in_sizes, int n_in,
                              void* d_out, int out_size, void* d_ws, size_t ws_size,
                              hipStream_t stream) {
  const float* X    = (const float*)d_in[0];
  const float* eh   = (const float*)d_in[1];
  const float* ec   = (const float*)d_in[2];
  const float* Wf   = (const float*)d_in[3];
  const float* bf_  = (const float*)d_in[4];
  const float* Wi   = (const float*)d_in[5];
  const float* bi_  = (const float*)d_in[6];
  const float* Wc   = (const float*)d_in[7];
  const float* bc_  = (const float*)d_in[8];
  const float* Wo   = (const float*)d_in[9];
  const float* bo_  = (const float*)d_in[10];
  float* out = (float*)d_out;

  unsigned* flags = (unsigned*)d_ws;                      // 512 B
  u64* hcbuf = (u64*)((char*)d_ws + 1024);                // [2][1024] (16 KB)

  hipMemsetAsync(d_ws, 0, 1024, stream);  // flags must start < 1 each call

  hipFuncSetAttribute((const void*)lstm_seq,
                      hipFuncAttributeMaxDynamicSharedMemorySize, LDSB);

  void* args[] = {(void*)&X, (void*)&eh, (void*)&ec,
                  (void*)&Wf, (void*)&bf_, (void*)&Wi, (void*)&bi_,
                  (void*)&Wc, (void*)&bc_, (void*)&Wo, (void*)&bo_,
                  (void*)&out, (void*)&hcbuf, (void*)&flags};
  hipError_t e = hipLaunchCooperativeKernel((const void*)lstm_seq,
                                            dim3(NBLK), dim3(NTHR),
                                            args, LDSB, stream);
  if (e != hipSuccess) {
    // plain-launch fallback: 128 blocks x 144KB LDS => 1 block/CU, co-resident
    lstm_seq<<<dim3(NBLK), dim3(NTHR), LDSB, stream>>>(
        X, eh, ec, Wf, bf_, Wi, bi_, Wc, bc_, Wo, bo_, out, hcbuf, flags);
  }
}